// Round 14
// baseline (133.020 us; speedup 1.0000x reference)
//
#include <hip/hip_runtime.h>
#include <math.h>

#define T_FRAMES 1025
#define TSTRIDE  1032          // row stride for Ht; 1032*8 = 129*64 -> rows 64B-aligned
#define BATCH    4
#define LWAV     131072
#define KWC      1023
#define MFFT     2048
#define PI_F     3.14159265358979323846f

struct c32 { float r, i; };
__device__ __forceinline__ c32 mkc(float r, float i){ c32 z; z.r=r; z.i=i; return z; }
__device__ __forceinline__ c32 cadd(c32 a, c32 b){ return mkc(a.r+b.r, a.i+b.i); }
__device__ __forceinline__ c32 csub(c32 a, c32 b){ return mkc(a.r-b.r, a.i-b.i); }
__device__ __forceinline__ c32 cmul(c32 a, c32 b){ return mkc(a.r*b.r - a.i*b.i, a.r*b.i + a.i*b.r); }
__device__ __forceinline__ c32 cni(c32 a){ return mkc(a.i, -a.r); }           // a * (-i)
#define C8F 0.70710678118654752440f
__device__ __forceinline__ c32 c8p(c32 a){ return mkc(C8F*(a.r+a.i), C8F*(a.i-a.r)); }   // * e^{-i pi/4}
__device__ __forceinline__ c32 c8m(c32 a){ return mkc(C8F*(a.i-a.r), -C8F*(a.r+a.i)); }  // * e^{-i 3pi/4}

__device__ __forceinline__ int pX(int j){ return j + (j >> 5); }
__device__ __forceinline__ int pS(int j){ return j + (j >> 3); }
__device__ __forceinline__ int rev9(int j){ return (int)(__brev((unsigned)j) >> 23); }

// e^{-2*pi*i*r/2048} via fast HW sincos
__device__ __forceinline__ c32 wexp(int r) {
    float s, c;
    __sincosf((float)r * (-PI_F / 1024.0f), &s, &c);
    return mkc(c, s);
}

// ---- radix-8 DIF step; w3 = W^{pos} of current level
__device__ __forceinline__ void dif8_tw(c32 y[8], c32 w3) {
    c32 w2 = cmul(w3, w3), w1 = cmul(w2, w2);
    c32 u[8], v[8], d;
    d = csub(y[0], y[4]); u[0] = cadd(y[0], y[4]); u[4] = cmul(d, w3);
    d = csub(y[1], y[5]); u[1] = cadd(y[1], y[5]); u[5] = c8p(cmul(d, w3));
    d = csub(y[2], y[6]); u[2] = cadd(y[2], y[6]); u[6] = cni(cmul(d, w3));
    d = csub(y[3], y[7]); u[3] = cadd(y[3], y[7]); u[7] = c8m(cmul(d, w3));
    d = csub(u[0], u[2]); v[0] = cadd(u[0], u[2]); v[2] = cmul(d, w2);
    d = csub(u[1], u[3]); v[1] = cadd(u[1], u[3]); v[3] = cni(cmul(d, w2));
    d = csub(u[4], u[6]); v[4] = cadd(u[4], u[6]); v[6] = cmul(d, w2);
    d = csub(u[5], u[7]); v[5] = cadd(u[5], u[7]); v[7] = cni(cmul(d, w2));
    d = csub(v[0], v[1]); y[0] = cadd(v[0], v[1]); y[1] = cmul(d, w1);
    d = csub(v[2], v[3]); y[2] = cadd(v[2], v[3]); y[3] = cmul(d, w1);
    d = csub(v[4], v[5]); y[4] = cadd(v[4], v[5]); y[5] = cmul(d, w1);
    d = csub(v[6], v[7]); y[6] = cadd(v[6], v[7]); y[7] = cmul(d, w1);
}
__device__ __forceinline__ void dif8_nt(c32 y[8]) {
    c32 u[8], v[8], d;
    d = csub(y[0], y[4]); u[0] = cadd(y[0], y[4]); u[4] = d;
    d = csub(y[1], y[5]); u[1] = cadd(y[1], y[5]); u[5] = c8p(d);
    d = csub(y[2], y[6]); u[2] = cadd(y[2], y[6]); u[6] = cni(d);
    d = csub(y[3], y[7]); u[3] = cadd(y[3], y[7]); u[7] = c8m(d);
    d = csub(u[0], u[2]); v[0] = cadd(u[0], u[2]); v[2] = d;
    d = csub(u[1], u[3]); v[1] = cadd(u[1], u[3]); v[3] = cni(d);
    d = csub(u[4], u[6]); v[4] = cadd(u[4], u[6]); v[6] = d;
    d = csub(u[5], u[7]); v[5] = cadd(u[5], u[7]); v[7] = cni(d);
    d = csub(v[0], v[1]); y[0] = cadd(v[0], v[1]); y[1] = d;
    d = csub(v[2], v[3]); y[2] = cadd(v[2], v[3]); y[3] = d;
    d = csub(v[4], v[5]); y[4] = cadd(v[4], v[5]); y[5] = d;
    d = csub(v[6], v[7]); y[6] = cadd(v[6], v[7]); y[7] = d;
}
__device__ __forceinline__ void dit8_tw(c32 y[8], c32 w3) {
    c32 w2 = cmul(w3, w3), w1 = cmul(w2, w2);
    c32 u[8], v[8], t;
    t = cmul(y[1], w1); u[0] = cadd(y[0], t); u[1] = csub(y[0], t);
    t = cmul(y[3], w1); u[2] = cadd(y[2], t); u[3] = csub(y[2], t);
    t = cmul(y[5], w1); u[4] = cadd(y[4], t); u[5] = csub(y[4], t);
    t = cmul(y[7], w1); u[6] = cadd(y[6], t); u[7] = csub(y[6], t);
    t = cmul(u[2], w2);      v[0] = cadd(u[0], t); v[2] = csub(u[0], t);
    t = cni(cmul(u[3], w2)); v[1] = cadd(u[1], t); v[3] = csub(u[1], t);
    t = cmul(u[6], w2);      v[4] = cadd(u[4], t); v[6] = csub(u[4], t);
    t = cni(cmul(u[7], w2)); v[5] = cadd(u[5], t); v[7] = csub(u[5], t);
    t = cmul(v[4], w3);      y[0] = cadd(v[0], t); y[4] = csub(v[0], t);
    t = c8p(cmul(v[5], w3)); y[1] = cadd(v[1], t); y[5] = csub(v[1], t);
    t = cni(cmul(v[6], w3)); y[2] = cadd(v[2], t); y[6] = csub(v[2], t);
    t = c8m(cmul(v[7], w3)); y[3] = cadd(v[3], t); y[7] = csub(v[3], t);
}
__device__ __forceinline__ void dit8_nt(c32 y[8]) {
    c32 u[8], v[8], t;
    u[0] = cadd(y[0], y[1]); u[1] = csub(y[0], y[1]);
    u[2] = cadd(y[2], y[3]); u[3] = csub(y[2], y[3]);
    u[4] = cadd(y[4], y[5]); u[5] = csub(y[4], y[5]);
    u[6] = cadd(y[6], y[7]); u[7] = csub(y[6], y[7]);
    t = u[2];      v[0] = cadd(u[0], t); v[2] = csub(u[0], t);
    t = cni(u[3]); v[1] = cadd(u[1], t); v[3] = csub(u[1], t);
    t = u[6];      v[4] = cadd(u[4], t); v[6] = csub(u[4], t);
    t = cni(u[7]); v[5] = cadd(u[5], t); v[7] = csub(u[5], t);
    t = v[4];      y[0] = cadd(v[0], t); y[4] = csub(v[0], t);
    t = c8p(v[5]); y[1] = cadd(v[1], t); y[5] = csub(v[1], t);
    t = cni(v[6]); y[2] = cadd(v[2], t); y[6] = csub(v[2], t);
    t = c8m(v[7]); y[3] = cadd(v[3], t); y[7] = csub(v[3], t);
}
__device__ __forceinline__ void dif4(c32 y[4]) {
    c32 u0 = cadd(y[0], y[2]), d0 = csub(y[0], y[2]);
    c32 u1 = cadd(y[1], y[3]), d1 = cni(csub(y[1], y[3]));
    y[0] = cadd(u0, u1); y[1] = csub(u0, u1);
    y[2] = cadd(d0, d1); y[3] = csub(d0, d1);
}
__device__ __forceinline__ void dit4(c32 y[4], c32 w) {
    c32 w2 = cmul(w, w);
    c32 t1 = cmul(y[1], w2); c32 u0 = cadd(y[0], t1), u1 = csub(y[0], t1);
    c32 t3 = cmul(y[3], w2); c32 u2 = cadd(y[2], t3), u3 = csub(y[2], t3);
    c32 s2 = cmul(u2, w);      y[0] = cadd(u0, s2); y[2] = csub(u0, s2);
    c32 s3 = cni(cmul(u3, w)); y[1] = cadd(u1, s3); y[3] = csub(u1, s3);
}

// ---------------- stage1 (R11 version): blocks 0..515 = STFT (8 frames/block);
// 516..522 = alpha-FFT; 523 zeroes out.
__global__ __launch_bounds__(256) void stage1_kernel(const float* __restrict__ wave,
                                                     const float* __restrict__ win,
                                                     const float* __restrict__ ar,
                                                     const float* __restrict__ ai,
                                                     float2* __restrict__ Ht,
                                                     float2* __restrict__ Afbr,
                                                     float* __restrict__ out) {
    __shared__ float lds[9216];      // stft: Fr[8][576] | Fi[8][576]; afft: Xr[2112] | Xi[2112]
    const int tid = threadIdx.x;

    if (blockIdx.x < 516) {
        float* Fr = lds;             // [8][576] flattened
        float* Fi = lds + 4608;
        const int w = tid >> 6, l = tid & 63;
        const int b = blockIdx.x / 129;
        const int t0 = (blockIdx.x - b * 129) << 3;
        const float* wb = wave + (size_t)b * LWAV;

        for (int pass = 0; pass < 2; ++pass) {
            const int j = w + (pass << 2);
            const int t = t0 + j;
            if (t < T_FRAMES) {
                c32 y[8];
#pragma unroll
                for (int k = 0; k < 8; ++k) {
                    int s = l + (k << 6);
                    int posn = t * 128 + s - 256;
                    int ix = posn < 0 ? -posn : (posn >= LWAV ? 2 * LWAV - 2 - posn : posn);
                    y[k] = mkc(wb[ix] * win[s], 0.f);
                }
                dif8_tw(y, wexp(l << 2));
#pragma unroll
                for (int k = 0; k < 8; ++k) { int p = pS(l + (k << 6)); Fr[j*576+p] = y[k].r; Fi[j*576+p] = y[k].i; }
                __builtin_amdgcn_wave_barrier();
                {
                    int base = ((l >> 3) << 6) + (l & 7);
#pragma unroll
                    for (int k = 0; k < 8; ++k) { int p = pS(base + (k << 3)); y[k] = mkc(Fr[j*576+p], Fi[j*576+p]); }
                    dif8_tw(y, wexp((l & 7) << 5));
#pragma unroll
                    for (int k = 0; k < 8; ++k) { int p = pS(base + (k << 3)); Fr[j*576+p] = y[k].r; Fi[j*576+p] = y[k].i; }
                }
                __builtin_amdgcn_wave_barrier();
                {
#pragma unroll
                    for (int k = 0; k < 8; ++k) { int p = pS((l << 3) + k); y[k] = mkc(Fr[j*576+p], Fi[j*576+p]); }
                    dif8_nt(y);
#pragma unroll
                    for (int k = 0; k < 8; ++k) { int p = pS((l << 3) + k); Fr[j*576+p] = y[k].r; Fi[j*576+p] = y[k].i; }
                }
            }
        }
        __syncthreads();
        // transposed writeout: rows p = tid, tid+256; skip rows whose bin > 256
        const bool full = (t0 + 7 < T_FRAMES);
#pragma unroll
        for (int h = 0; h < 2; ++h) {
            int p = tid + (h << 8);
            int bin = rev9(p);
            if (bin > 256) continue;
            int ps = pS(p);
            size_t rowbase = (size_t)(b * 512 + p) * TSTRIDE + t0;
            if (full) {
                float4* dst = (float4*)(Ht + rowbase);
#pragma unroll
                for (int jj = 0; jj < 4; ++jj)
                    dst[jj] = make_float4(Fr[2*jj*576+ps], Fi[2*jj*576+ps], Fr[(2*jj+1)*576+ps], Fi[(2*jj+1)*576+ps]);
            } else {
                for (int jj = 0; jj < 8; ++jj)
                    if (t0 + jj < T_FRAMES) Ht[rowbase + jj] = make_float2(Fr[jj*576+ps], Fi[jj*576+ps]);
            }
        }
    } else if (blockIdx.x < 523) {
        // ---- alpha FFT: Af_br[q][p] = conj(DIF2048(conj(alpha_q) zero-pad))[p]
        float* Xr = lds;
        float* Xi = lds + 2112;
        const int q = blockIdx.x - 516;
        c32 y[8];
#pragma unroll
        for (int k = 0; k < 8; ++k) {
            int j = tid + (k << 8);
            y[k] = (j < KWC) ? mkc(ar[q * KWC + j], -ai[q * KWC + j]) : mkc(0.f, 0.f);
        }
        dif8_tw(y, wexp(tid));
#pragma unroll
        for (int k = 0; k < 8; ++k) { int p = pX(tid + (k << 8)); Xr[p] = y[k].r; Xi[p] = y[k].i; }
        __syncthreads();
        {
            int base = ((tid >> 5) << 8) + (tid & 31);
#pragma unroll
            for (int k = 0; k < 8; ++k) { int p = pX(base + (k << 5)); y[k] = mkc(Xr[p], Xi[p]); }
            dif8_tw(y, wexp((tid & 31) << 3));
#pragma unroll
            for (int k = 0; k < 8; ++k) { int p = pX(base + (k << 5)); Xr[p] = y[k].r; Xi[p] = y[k].i; }
        }
        __syncthreads();
        {
            int base = ((tid & 63) << 5) + (tid >> 6);
#pragma unroll
            for (int k = 0; k < 8; ++k) { int p = pX(base + (k << 2)); y[k] = mkc(Xr[p], Xi[p]); }
            dif8_tw(y, wexp((tid >> 6) << 6));
#pragma unroll
            for (int k = 0; k < 8; ++k) { int p = pX(base + (k << 2)); Xr[p] = y[k].r; Xi[p] = y[k].i; }
        }
        __syncthreads();
#pragma unroll
        for (int h = 0; h < 2; ++h) {
            int g = tid + (h << 8);
            c32 z4[4];
#pragma unroll
            for (int k = 0; k < 4; ++k) { int p = pX((g << 2) + k); z4[k] = mkc(Xr[p], Xi[p]); }
            dif4(z4);
#pragma unroll
            for (int k = 0; k < 4; ++k) Afbr[(q << 11) + (g << 2) + k] = make_float2(z4[k].r, -z4[k].i);
        }
    } else {
        if (tid == 0) *out = 0.f;
    }
}

// ---------------- conv: 512 threads = TWO independent rows (b0+rsel, n), one per
// half-block. Same grid 514 but 8 waves/block -> 16 waves/CU (2x latency hiding).
// Each half runs the proven single-row radix-8 phase code with et = tid & 255.
__global__ __launch_bounds__(512) void conv_kernel(const float2* __restrict__ Ht,
                                                   const float2* __restrict__ Afbr,
                                                   float* __restrict__ out) {
    __shared__ float lds[8448];   // row0: Xr|Xi (2112 each); row1: +4224
    const int tid = threadIdx.x;
    const int rsel = tid >> 8;                   // 0 or 1
    const int et = tid & 255;                    // element-thread within row
    float* Xr = lds + rsel * 4224;
    float* Xi = Xr + 2112;
    const int g = blockIdx.x;                    // 0..513
    const int half = g / 257;
    const int n = g - half * 257;                // bin 0..256
    const int b = (half << 1) + rsel;
    const int pr = rev9(n);                      // Ht row holding bin n

    const float2* row = Ht + (size_t)(b * 512 + pr) * TSTRIDE;
    c32 y[8];
    // DIF A (11,10,9): elements et + 256k
#pragma unroll
    for (int k = 0; k < 8; ++k) {
        int j = et + (k << 8);
        c32 v = mkc(0.f, 0.f);
        if (j < T_FRAMES) { float2 h = row[j]; v = mkc(h.x, h.y); }
        y[k] = v;
    }
    dif8_tw(y, wexp(et));
#pragma unroll
    for (int k = 0; k < 8; ++k) { int p = pX(et + (k << 8)); Xr[p] = y[k].r; Xi[p] = y[k].i; }
    __syncthreads();
    // DIF B (8,7,6)
    {
        int base = ((et >> 5) << 8) + (et & 31);
#pragma unroll
        for (int k = 0; k < 8; ++k) { int p = pX(base + (k << 5)); y[k] = mkc(Xr[p], Xi[p]); }
        dif8_tw(y, wexp((et & 31) << 3));
#pragma unroll
        for (int k = 0; k < 8; ++k) { int p = pX(base + (k << 5)); Xr[p] = y[k].r; Xi[p] = y[k].i; }
    }
    __syncthreads();
    // DIF C (5,4,3)
    {
        int base = ((et & 63) << 5) + (et >> 6);
#pragma unroll
        for (int k = 0; k < 8; ++k) { int p = pX(base + (k << 2)); y[k] = mkc(Xr[p], Xi[p]); }
        dif8_tw(y, wexp((et >> 6) << 6));
#pragma unroll
        for (int k = 0; k < 8; ++k) { int p = pX(base + (k << 2)); Xr[p] = y[k].r; Xi[p] = y[k].i; }
    }
    __syncthreads();
    // FUSED: DIF D (radix-4 x2) + pointwise + DIT A (1,2,3)
    {
        c32 p1 = wexp(-(n << 2));                      // e^{+2pi i n/512}
        c32 p2 = cmul(p1, p1);
        c32 p3 = cmul(p2, p1);
        const int a0 = et << 3;
        const int p0 = pX(a0);
        c32 z[8];
#pragma unroll
        for (int k = 0; k < 8; ++k) z[k] = mkc(Xr[p0 + k], Xi[p0 + k]);
        dif4(&z[0]);
        dif4(&z[4]);
        const float4* af4 = (const float4*)(Afbr + a0);
#pragma unroll
        for (int k = 0; k < 8; ++k) {
            float4 a;
            c32 Kk;
            a = af4[(3 << 10) + (k >> 1)];     // q'=0
            float ax = (k & 1) ? a.z : a.x, ay = (k & 1) ? a.w : a.y;
            Kk = mkc(ax, ay);
            a = af4[(4 << 10) + (k >> 1)]; ax = (k & 1) ? a.z : a.x; ay = (k & 1) ? a.w : a.y;
            Kk.r += p1.r * ax - p1.i * ay;  Kk.i += p1.r * ay + p1.i * ax;
            a = af4[(2 << 10) + (k >> 1)]; ax = (k & 1) ? a.z : a.x; ay = (k & 1) ? a.w : a.y;
            Kk.r += p1.r * ax + p1.i * ay;  Kk.i += p1.r * ay - p1.i * ax;
            a = af4[(5 << 10) + (k >> 1)]; ax = (k & 1) ? a.z : a.x; ay = (k & 1) ? a.w : a.y;
            Kk.r += p2.r * ax - p2.i * ay;  Kk.i += p2.r * ay + p2.i * ax;
            a = af4[(1 << 10) + (k >> 1)]; ax = (k & 1) ? a.z : a.x; ay = (k & 1) ? a.w : a.y;
            Kk.r += p2.r * ax + p2.i * ay;  Kk.i += p2.r * ay - p2.i * ax;
            a = af4[(6 << 10) + (k >> 1)]; ax = (k & 1) ? a.z : a.x; ay = (k & 1) ? a.w : a.y;
            Kk.r += p3.r * ax - p3.i * ay;  Kk.i += p3.r * ay + p3.i * ax;
            a = af4[(0 << 10) + (k >> 1)]; ax = (k & 1) ? a.z : a.x; ay = (k & 1) ? a.w : a.y;
            Kk.r += p3.r * ax + p3.i * ay;  Kk.i += p3.r * ay - p3.i * ax;
            c32 P = cmul(z[k], Kk);
            z[k] = mkc(P.r, -P.i);             // conj for inverse-via-forward
        }
        dit8_nt(z);
#pragma unroll
        for (int k = 0; k < 8; ++k) { Xr[p0 + k] = z[k].r; Xi[p0 + k] = z[k].i; }
    }
    __syncthreads();
    // DIT B (4,5,6)
    {
        int G = (((et & 63) >> 3) << 2) + (et >> 6);
        int pos = et & 7;
        int base = (G << 6) + pos;
#pragma unroll
        for (int k = 0; k < 8; ++k) { int p = pX(base + (k << 3)); y[k] = mkc(Xr[p], Xi[p]); }
        dit8_tw(y, wexp(pos << 5));
#pragma unroll
        for (int k = 0; k < 8; ++k) { int p = pX(base + (k << 3)); Xr[p] = y[k].r; Xi[p] = y[k].i; }
    }
    __syncthreads();
    // DIT C (7,8,9)
    {
        int base = ((et >> 6) << 9) + (et & 63);
#pragma unroll
        for (int k = 0; k < 8; ++k) { int p = pX(base + (k << 6)); y[k] = mkc(Xr[p], Xi[p]); }
        dit8_tw(y, wexp((et & 63) << 2));
#pragma unroll
        for (int k = 0; k < 8; ++k) { int p = pX(base + (k << 6)); Xr[p] = y[k].r; Xi[p] = y[k].i; }
    }
    __syncthreads();
    // DIT D (10,11) radix-4 + masked |.|^2; per-wave atomicAdd
    float local = 0.f;
#pragma unroll
    for (int h = 0; h < 2; ++h) {
        int pos = et + (h << 8);
        c32 z4[4];
#pragma unroll
        for (int k = 0; k < 4; ++k) { int p = pX(pos + (k << 9)); z4[k] = mkc(Xr[p], Xi[p]); }
        dit4(z4, wexp(pos));
        local += z4[0].r * z4[0].r + z4[0].i * z4[0].i;                 // s = pos < 514 always
        if (pos < 2)  local += z4[1].r * z4[1].r + z4[1].i * z4[1].i;   // s in {512,513}
        if (pos >= 1) local += z4[3].r * z4[3].r + z4[3].i * z4[3].i;   // s >= 1537
    }
    local *= (n == 0 || n == 256) ? 1.0f : 2.0f;       // mirror-row weight
#pragma unroll
    for (int off = 32; off >= 1; off >>= 1) local += __shfl_down(local, off);
    if ((tid & 63) == 0) {
        const float SCALE =
            (float)(1.0 / ((double)MFFT * (double)MFFT * (double)BATCH * (double)T_FRAMES));
        atomicAdd(out, local * SCALE);
    }
}

extern "C" void kernel_launch(void* const* d_in, const int* in_sizes, int n_in,
                              void* d_out, int out_size, void* d_ws, size_t ws_size,
                              hipStream_t stream) {
    (void)in_sizes; (void)n_in; (void)out_size; (void)ws_size;
    const float* wave   = (const float*)d_in[0];
    const float* window = (const float*)d_in[1];
    const float* ar     = (const float*)d_in[2];
    const float* ai     = (const float*)d_in[3];
    float* out = (float*)d_out;

    char* ws = (char*)d_ws;
    float2* Ht   = (float2*)ws;                          // 4*512*1032*8 = 16,908,288 B
    float2* Afbr = (float2*)(ws + 16908288);             // 7*2048*8    =    114,688 B

    stage1_kernel<<<524, 256, 0, stream>>>(wave, window, ar, ai, Ht, Afbr, out);
    conv_kernel<<<2 * 257, 512, 0, stream>>>(Ht, Afbr, out);
}

// Round 15
// 105.864 us; speedup vs baseline: 1.2565x; 1.2565x over previous
//
#include <hip/hip_runtime.h>
#include <math.h>

#define T_FRAMES 1025
#define TSTRIDE  1032          // row stride for Ht; 1032*8 = 129*64 -> rows 64B-aligned
#define BATCH    4
#define LWAV     131072
#define KWC      1023
#define MFFT     2048
#define PI_F     3.14159265358979323846f

struct c32 { float r, i; };
__device__ __forceinline__ c32 mkc(float r, float i){ c32 z; z.r=r; z.i=i; return z; }
__device__ __forceinline__ c32 cadd(c32 a, c32 b){ return mkc(a.r+b.r, a.i+b.i); }
__device__ __forceinline__ c32 csub(c32 a, c32 b){ return mkc(a.r-b.r, a.i-b.i); }
__device__ __forceinline__ c32 cmul(c32 a, c32 b){ return mkc(a.r*b.r - a.i*b.i, a.r*b.i + a.i*b.r); }
__device__ __forceinline__ c32 cni(c32 a){ return mkc(a.i, -a.r); }           // a * (-i)
#define C8F 0.70710678118654752440f
__device__ __forceinline__ c32 c8p(c32 a){ return mkc(C8F*(a.r+a.i), C8F*(a.i-a.r)); }   // * e^{-i pi/4}
__device__ __forceinline__ c32 c8m(c32 a){ return mkc(C8F*(a.i-a.r), -C8F*(a.r+a.i)); }  // * e^{-i 3pi/4}

__device__ __forceinline__ int pX(int j){ return j + (j >> 5); }
__device__ __forceinline__ int pS(int j){ return j + (j >> 3); }
__device__ __forceinline__ int rev9(int j){ return (int)(__brev((unsigned)j) >> 23); }

// e^{-2*pi*i*r/2048} via fast HW sincos
__device__ __forceinline__ c32 wexp(int r) {
    float s, c;
    __sincosf((float)r * (-PI_F / 1024.0f), &s, &c);
    return mkc(c, s);
}

// ---- radix-8 DIF step; w3 = W^{pos} of current level
__device__ __forceinline__ void dif8_tw(c32 y[8], c32 w3) {
    c32 w2 = cmul(w3, w3), w1 = cmul(w2, w2);
    c32 u[8], v[8], d;
    d = csub(y[0], y[4]); u[0] = cadd(y[0], y[4]); u[4] = cmul(d, w3);
    d = csub(y[1], y[5]); u[1] = cadd(y[1], y[5]); u[5] = c8p(cmul(d, w3));
    d = csub(y[2], y[6]); u[2] = cadd(y[2], y[6]); u[6] = cni(cmul(d, w3));
    d = csub(y[3], y[7]); u[3] = cadd(y[3], y[7]); u[7] = c8m(cmul(d, w3));
    d = csub(u[0], u[2]); v[0] = cadd(u[0], u[2]); v[2] = cmul(d, w2);
    d = csub(u[1], u[3]); v[1] = cadd(u[1], u[3]); v[3] = cni(cmul(d, w2));
    d = csub(u[4], u[6]); v[4] = cadd(u[4], u[6]); v[6] = cmul(d, w2);
    d = csub(u[5], u[7]); v[5] = cadd(u[5], u[7]); v[7] = cni(cmul(d, w2));
    d = csub(v[0], v[1]); y[0] = cadd(v[0], v[1]); y[1] = cmul(d, w1);
    d = csub(v[2], v[3]); y[2] = cadd(v[2], v[3]); y[3] = cmul(d, w1);
    d = csub(v[4], v[5]); y[4] = cadd(v[4], v[5]); y[5] = cmul(d, w1);
    d = csub(v[6], v[7]); y[6] = cadd(v[6], v[7]); y[7] = cmul(d, w1);
}
// ---- same but with y[5]=y[6]=y[7]==0 (exact specialization, identical math)
__device__ __forceinline__ void dif8_tw_z567(c32 y[8], c32 w3) {
    c32 w2 = cmul(w3, w3), w1 = cmul(w2, w2);
    c32 u[8], v[8], d;
    d = csub(y[0], y[4]); u[0] = cadd(y[0], y[4]); u[4] = cmul(d, w3);
    u[1] = y[1]; u[5] = c8p(cmul(y[1], w3));
    u[2] = y[2]; u[6] = cni(cmul(y[2], w3));
    u[3] = y[3]; u[7] = c8m(cmul(y[3], w3));
    d = csub(u[0], u[2]); v[0] = cadd(u[0], u[2]); v[2] = cmul(d, w2);
    d = csub(u[1], u[3]); v[1] = cadd(u[1], u[3]); v[3] = cni(cmul(d, w2));
    d = csub(u[4], u[6]); v[4] = cadd(u[4], u[6]); v[6] = cmul(d, w2);
    d = csub(u[5], u[7]); v[5] = cadd(u[5], u[7]); v[7] = cni(cmul(d, w2));
    d = csub(v[0], v[1]); y[0] = cadd(v[0], v[1]); y[1] = cmul(d, w1);
    d = csub(v[2], v[3]); y[2] = cadd(v[2], v[3]); y[3] = cmul(d, w1);
    d = csub(v[4], v[5]); y[4] = cadd(v[4], v[5]); y[5] = cmul(d, w1);
    d = csub(v[6], v[7]); y[6] = cadd(v[6], v[7]); y[7] = cmul(d, w1);
}
__device__ __forceinline__ void dif8_nt(c32 y[8]) {
    c32 u[8], v[8], d;
    d = csub(y[0], y[4]); u[0] = cadd(y[0], y[4]); u[4] = d;
    d = csub(y[1], y[5]); u[1] = cadd(y[1], y[5]); u[5] = c8p(d);
    d = csub(y[2], y[6]); u[2] = cadd(y[2], y[6]); u[6] = cni(d);
    d = csub(y[3], y[7]); u[3] = cadd(y[3], y[7]); u[7] = c8m(d);
    d = csub(u[0], u[2]); v[0] = cadd(u[0], u[2]); v[2] = d;
    d = csub(u[1], u[3]); v[1] = cadd(u[1], u[3]); v[3] = cni(d);
    d = csub(u[4], u[6]); v[4] = cadd(u[4], u[6]); v[6] = d;
    d = csub(u[5], u[7]); v[5] = cadd(u[5], u[7]); v[7] = cni(d);
    d = csub(v[0], v[1]); y[0] = cadd(v[0], v[1]); y[1] = d;
    d = csub(v[2], v[3]); y[2] = cadd(v[2], v[3]); y[3] = d;
    d = csub(v[4], v[5]); y[4] = cadd(v[4], v[5]); y[5] = d;
    d = csub(v[6], v[7]); y[6] = cadd(v[6], v[7]); y[7] = d;
}
__device__ __forceinline__ void dit8_tw(c32 y[8], c32 w3) {
    c32 w2 = cmul(w3, w3), w1 = cmul(w2, w2);
    c32 u[8], v[8], t;
    t = cmul(y[1], w1); u[0] = cadd(y[0], t); u[1] = csub(y[0], t);
    t = cmul(y[3], w1); u[2] = cadd(y[2], t); u[3] = csub(y[2], t);
    t = cmul(y[5], w1); u[4] = cadd(y[4], t); u[5] = csub(y[4], t);
    t = cmul(y[7], w1); u[6] = cadd(y[6], t); u[7] = csub(y[6], t);
    t = cmul(u[2], w2);      v[0] = cadd(u[0], t); v[2] = csub(u[0], t);
    t = cni(cmul(u[3], w2)); v[1] = cadd(u[1], t); v[3] = csub(u[1], t);
    t = cmul(u[6], w2);      v[4] = cadd(u[4], t); v[6] = csub(u[4], t);
    t = cni(cmul(u[7], w2)); v[5] = cadd(u[5], t); v[7] = csub(u[5], t);
    t = cmul(v[4], w3);      y[0] = cadd(v[0], t); y[4] = csub(v[0], t);
    t = c8p(cmul(v[5], w3)); y[1] = cadd(v[1], t); y[5] = csub(v[1], t);
    t = cni(cmul(v[6], w3)); y[2] = cadd(v[2], t); y[6] = csub(v[2], t);
    t = c8m(cmul(v[7], w3)); y[3] = cadd(v[3], t); y[7] = csub(v[3], t);
}
__device__ __forceinline__ void dit8_nt(c32 y[8]) {
    c32 u[8], v[8], t;
    u[0] = cadd(y[0], y[1]); u[1] = csub(y[0], y[1]);
    u[2] = cadd(y[2], y[3]); u[3] = csub(y[2], y[3]);
    u[4] = cadd(y[4], y[5]); u[5] = csub(y[4], y[5]);
    u[6] = cadd(y[6], y[7]); u[7] = csub(y[6], y[7]);
    t = u[2];      v[0] = cadd(u[0], t); v[2] = csub(u[0], t);
    t = cni(u[3]); v[1] = cadd(u[1], t); v[3] = csub(u[1], t);
    t = u[6];      v[4] = cadd(u[4], t); v[6] = csub(u[4], t);
    t = cni(u[7]); v[5] = cadd(u[5], t); v[7] = csub(u[5], t);
    t = v[4];      y[0] = cadd(v[0], t); y[4] = csub(v[0], t);
    t = c8p(v[5]); y[1] = cadd(v[1], t); y[5] = csub(v[1], t);
    t = cni(v[6]); y[2] = cadd(v[2], t); y[6] = csub(v[2], t);
    t = c8m(v[7]); y[3] = cadd(v[3], t); y[7] = csub(v[3], t);
}
__device__ __forceinline__ void dif4(c32 y[4]) {
    c32 u0 = cadd(y[0], y[2]), d0 = csub(y[0], y[2]);
    c32 u1 = cadd(y[1], y[3]), d1 = cni(csub(y[1], y[3]));
    y[0] = cadd(u0, u1); y[1] = csub(u0, u1);
    y[2] = cadd(d0, d1); y[3] = csub(d0, d1);
}
__device__ __forceinline__ void dit4(c32 y[4], c32 w) {
    c32 w2 = cmul(w, w);
    c32 t1 = cmul(y[1], w2); c32 u0 = cadd(y[0], t1), u1 = csub(y[0], t1);
    c32 t3 = cmul(y[3], w2); c32 u2 = cadd(y[2], t3), u3 = csub(y[2], t3);
    c32 s2 = cmul(u2, w);      y[0] = cadd(u0, s2); y[2] = csub(u0, s2);
    c32 s3 = cni(cmul(u3, w)); y[1] = cadd(u1, s3); y[3] = csub(u1, s3);
}

// ---------------- stage1 (R11 version): blocks 0..515 = STFT (8 frames/block);
// 516..522 = alpha-FFT; 523 zeroes out.
__global__ __launch_bounds__(256) void stage1_kernel(const float* __restrict__ wave,
                                                     const float* __restrict__ win,
                                                     const float* __restrict__ ar,
                                                     const float* __restrict__ ai,
                                                     float2* __restrict__ Ht,
                                                     float2* __restrict__ Afbr,
                                                     float* __restrict__ out) {
    __shared__ float lds[9216];      // stft: Fr[8][576] | Fi[8][576]; afft: Xr[2112] | Xi[2112]
    const int tid = threadIdx.x;

    if (blockIdx.x < 516) {
        float* Fr = lds;             // [8][576] flattened
        float* Fi = lds + 4608;
        const int w = tid >> 6, l = tid & 63;
        const int b = blockIdx.x / 129;
        const int t0 = (blockIdx.x - b * 129) << 3;
        const float* wb = wave + (size_t)b * LWAV;

        for (int pass = 0; pass < 2; ++pass) {
            const int j = w + (pass << 2);
            const int t = t0 + j;
            if (t < T_FRAMES) {
                c32 y[8];
#pragma unroll
                for (int k = 0; k < 8; ++k) {
                    int s = l + (k << 6);
                    int posn = t * 128 + s - 256;
                    int ix = posn < 0 ? -posn : (posn >= LWAV ? 2 * LWAV - 2 - posn : posn);
                    y[k] = mkc(wb[ix] * win[s], 0.f);
                }
                dif8_tw(y, wexp(l << 2));
#pragma unroll
                for (int k = 0; k < 8; ++k) { int p = pS(l + (k << 6)); Fr[j*576+p] = y[k].r; Fi[j*576+p] = y[k].i; }
                __builtin_amdgcn_wave_barrier();
                {
                    int base = ((l >> 3) << 6) + (l & 7);
#pragma unroll
                    for (int k = 0; k < 8; ++k) { int p = pS(base + (k << 3)); y[k] = mkc(Fr[j*576+p], Fi[j*576+p]); }
                    dif8_tw(y, wexp((l & 7) << 5));
#pragma unroll
                    for (int k = 0; k < 8; ++k) { int p = pS(base + (k << 3)); Fr[j*576+p] = y[k].r; Fi[j*576+p] = y[k].i; }
                }
                __builtin_amdgcn_wave_barrier();
                {
#pragma unroll
                    for (int k = 0; k < 8; ++k) { int p = pS((l << 3) + k); y[k] = mkc(Fr[j*576+p], Fi[j*576+p]); }
                    dif8_nt(y);
#pragma unroll
                    for (int k = 0; k < 8; ++k) { int p = pS((l << 3) + k); Fr[j*576+p] = y[k].r; Fi[j*576+p] = y[k].i; }
                }
            }
        }
        __syncthreads();
        // transposed writeout: rows p = tid, tid+256; skip rows whose bin > 256
        const bool full = (t0 + 7 < T_FRAMES);
#pragma unroll
        for (int h = 0; h < 2; ++h) {
            int p = tid + (h << 8);
            int bin = rev9(p);
            if (bin > 256) continue;
            int ps = pS(p);
            size_t rowbase = (size_t)(b * 512 + p) * TSTRIDE + t0;
            if (full) {
                float4* dst = (float4*)(Ht + rowbase);
#pragma unroll
                for (int jj = 0; jj < 4; ++jj)
                    dst[jj] = make_float4(Fr[2*jj*576+ps], Fi[2*jj*576+ps], Fr[(2*jj+1)*576+ps], Fi[(2*jj+1)*576+ps]);
            } else {
                for (int jj = 0; jj < 8; ++jj)
                    if (t0 + jj < T_FRAMES) Ht[rowbase + jj] = make_float2(Fr[jj*576+ps], Fi[jj*576+ps]);
            }
        }
    } else if (blockIdx.x < 523) {
        // ---- alpha FFT: Af_br[q][p] = conj(DIF2048(conj(alpha_q) zero-pad))[p]
        float* Xr = lds;
        float* Xi = lds + 2112;
        const int q = blockIdx.x - 516;
        c32 y[8];
#pragma unroll
        for (int k = 0; k < 8; ++k) {
            int j = tid + (k << 8);
            y[k] = (j < KWC) ? mkc(ar[q * KWC + j], -ai[q * KWC + j]) : mkc(0.f, 0.f);
        }
        dif8_tw(y, wexp(tid));
#pragma unroll
        for (int k = 0; k < 8; ++k) { int p = pX(tid + (k << 8)); Xr[p] = y[k].r; Xi[p] = y[k].i; }
        __syncthreads();
        {
            int base = ((tid >> 5) << 8) + (tid & 31);
#pragma unroll
            for (int k = 0; k < 8; ++k) { int p = pX(base + (k << 5)); y[k] = mkc(Xr[p], Xi[p]); }
            dif8_tw(y, wexp((tid & 31) << 3));
#pragma unroll
            for (int k = 0; k < 8; ++k) { int p = pX(base + (k << 5)); Xr[p] = y[k].r; Xi[p] = y[k].i; }
        }
        __syncthreads();
        {
            int base = ((tid & 63) << 5) + (tid >> 6);
#pragma unroll
            for (int k = 0; k < 8; ++k) { int p = pX(base + (k << 2)); y[k] = mkc(Xr[p], Xi[p]); }
            dif8_tw(y, wexp((tid >> 6) << 6));
#pragma unroll
            for (int k = 0; k < 8; ++k) { int p = pX(base + (k << 2)); Xr[p] = y[k].r; Xi[p] = y[k].i; }
        }
        __syncthreads();
#pragma unroll
        for (int h = 0; h < 2; ++h) {
            int g = tid + (h << 8);
            c32 z4[4];
#pragma unroll
            for (int k = 0; k < 4; ++k) { int p = pX((g << 2) + k); z4[k] = mkc(Xr[p], Xi[p]); }
            dif4(z4);
#pragma unroll
            for (int k = 0; k < 4; ++k) Afbr[(q << 11) + (g << 2) + k] = make_float2(z4[k].r, -z4[k].i);
        }
    } else {
        if (tid == 0) *out = 0.f;
    }
}

// ---------------- conv (R11 structure): TWO rows (b0,n),(b0+1,n) per 256-thread block.
// Rows share all twiddles, phase factors, and the per-element Kk construction.
// Phase A zero-pruned: j = tid+256k < 1025 always for k<=3; j=1024 only for tid==0;
// k>=5 identically zero. Final reduction: per-wave atomicAdd.
__global__ __launch_bounds__(256) void conv_kernel(const float2* __restrict__ Ht,
                                                   const float2* __restrict__ Afbr,
                                                   float* __restrict__ out) {
    __shared__ float lds[8448];   // X0r|X0i|X1r|X1i (4*2112)
    float* X0r = lds;
    float* X0i = lds + 2112;
    float* X1r = lds + 4224;
    float* X1i = lds + 6336;
    const int tid = threadIdx.x;
    const int g = blockIdx.x;                    // 0..513
    const int half = g / 257;
    const int n = g - half * 257;                // bin 0..256
    const int b0 = half << 1;
    const int pr = rev9(n);                      // Ht row holding bin n

    const float2* row0 = Ht + (size_t)(b0 * 512 + pr) * TSTRIDE;
    const float2* row1 = Ht + (size_t)((b0 + 1) * 512 + pr) * TSTRIDE;

    c32 y0[8], y1[8];
    // DIF A (11,10,9): k=0..3 unconditional loads; k=4 only tid==0; k=5..7 zero
#pragma unroll
    for (int k = 0; k < 4; ++k) {
        int j = tid + (k << 8);
        float2 h0 = row0[j]; y0[k] = mkc(h0.x, h0.y);
        float2 h1 = row1[j]; y1[k] = mkc(h1.x, h1.y);
    }
    y0[4] = mkc(0.f, 0.f); y1[4] = mkc(0.f, 0.f);
    if (tid == 0) {
        float2 h0 = row0[1024]; y0[4] = mkc(h0.x, h0.y);
        float2 h1 = row1[1024]; y1[4] = mkc(h1.x, h1.y);
    }
    {
        c32 w3 = wexp(tid);
        dif8_tw_z567(y0, w3);
        dif8_tw_z567(y1, w3);
#pragma unroll
        for (int k = 0; k < 8; ++k) {
            int p = pX(tid + (k << 8));
            X0r[p] = y0[k].r; X0i[p] = y0[k].i;
            X1r[p] = y1[k].r; X1i[p] = y1[k].i;
        }
    }
    __syncthreads();
    // DIF B (8,7,6)
    {
        int base = ((tid >> 5) << 8) + (tid & 31);
#pragma unroll
        for (int k = 0; k < 8; ++k) {
            int p = pX(base + (k << 5));
            y0[k] = mkc(X0r[p], X0i[p]);
            y1[k] = mkc(X1r[p], X1i[p]);
        }
        c32 w3 = wexp((tid & 31) << 3);
        dif8_tw(y0, w3);
        dif8_tw(y1, w3);
#pragma unroll
        for (int k = 0; k < 8; ++k) {
            int p = pX(base + (k << 5));
            X0r[p] = y0[k].r; X0i[p] = y0[k].i;
            X1r[p] = y1[k].r; X1i[p] = y1[k].i;
        }
    }
    __syncthreads();
    // DIF C (5,4,3)
    {
        int base = ((tid & 63) << 5) + (tid >> 6);
#pragma unroll
        for (int k = 0; k < 8; ++k) {
            int p = pX(base + (k << 2));
            y0[k] = mkc(X0r[p], X0i[p]);
            y1[k] = mkc(X1r[p], X1i[p]);
        }
        c32 w3 = wexp((tid >> 6) << 6);
        dif8_tw(y0, w3);
        dif8_tw(y1, w3);
#pragma unroll
        for (int k = 0; k < 8; ++k) {
            int p = pX(base + (k << 2));
            X0r[p] = y0[k].r; X0i[p] = y0[k].i;
            X1r[p] = y1[k].r; X1i[p] = y1[k].i;
        }
    }
    __syncthreads();
    // FUSED: DIF D (radix-4 x2) + pointwise (Kk computed ONCE for both rows) + DIT A
    {
        c32 p1 = wexp(-(n << 2));                      // e^{+2pi i n/512}
        c32 p2 = cmul(p1, p1);
        c32 p3 = cmul(p2, p1);
        const int a0 = tid << 3;
        const int p0 = pX(a0);
#pragma unroll
        for (int k = 0; k < 8; ++k) {
            y0[k] = mkc(X0r[p0 + k], X0i[p0 + k]);
            y1[k] = mkc(X1r[p0 + k], X1i[p0 + k]);
        }
        dif4(&y0[0]); dif4(&y0[4]);
        dif4(&y1[0]); dif4(&y1[4]);
        const float4* af4 = (const float4*)(Afbr + a0);
#pragma unroll
        for (int k = 0; k < 8; ++k) {
            float4 a;
            c32 Kk;
            a = af4[(3 << 10) + (k >> 1)];     // q'=0
            float ax = (k & 1) ? a.z : a.x, ay = (k & 1) ? a.w : a.y;
            Kk = mkc(ax, ay);
            a = af4[(4 << 10) + (k >> 1)]; ax = (k & 1) ? a.z : a.x; ay = (k & 1) ? a.w : a.y;
            Kk.r += p1.r * ax - p1.i * ay;  Kk.i += p1.r * ay + p1.i * ax;
            a = af4[(2 << 10) + (k >> 1)]; ax = (k & 1) ? a.z : a.x; ay = (k & 1) ? a.w : a.y;
            Kk.r += p1.r * ax + p1.i * ay;  Kk.i += p1.r * ay - p1.i * ax;
            a = af4[(5 << 10) + (k >> 1)]; ax = (k & 1) ? a.z : a.x; ay = (k & 1) ? a.w : a.y;
            Kk.r += p2.r * ax - p2.i * ay;  Kk.i += p2.r * ay + p2.i * ax;
            a = af4[(1 << 10) + (k >> 1)]; ax = (k & 1) ? a.z : a.x; ay = (k & 1) ? a.w : a.y;
            Kk.r += p2.r * ax + p2.i * ay;  Kk.i += p2.r * ay - p2.i * ax;
            a = af4[(6 << 10) + (k >> 1)]; ax = (k & 1) ? a.z : a.x; ay = (k & 1) ? a.w : a.y;
            Kk.r += p3.r * ax - p3.i * ay;  Kk.i += p3.r * ay + p3.i * ax;
            a = af4[(0 << 10) + (k >> 1)]; ax = (k & 1) ? a.z : a.x; ay = (k & 1) ? a.w : a.y;
            Kk.r += p3.r * ax + p3.i * ay;  Kk.i += p3.r * ay - p3.i * ax;
            c32 P0 = cmul(y0[k], Kk);
            c32 P1 = cmul(y1[k], Kk);
            y0[k] = mkc(P0.r, -P0.i);          // conj for inverse-via-forward
            y1[k] = mkc(P1.r, -P1.i);
        }
        dit8_nt(y0);
        dit8_nt(y1);
#pragma unroll
        for (int k = 0; k < 8; ++k) {
            X0r[p0 + k] = y0[k].r; X0i[p0 + k] = y0[k].i;
            X1r[p0 + k] = y1[k].r; X1i[p0 + k] = y1[k].i;
        }
    }
    __syncthreads();
    // DIT B (4,5,6)
    {
        int G = (((tid & 63) >> 3) << 2) + (tid >> 6);
        int pos = tid & 7;
        int base = (G << 6) + pos;
#pragma unroll
        for (int k = 0; k < 8; ++k) {
            int p = pX(base + (k << 3));
            y0[k] = mkc(X0r[p], X0i[p]);
            y1[k] = mkc(X1r[p], X1i[p]);
        }
        c32 w3 = wexp(pos << 5);
        dit8_tw(y0, w3);
        dit8_tw(y1, w3);
#pragma unroll
        for (int k = 0; k < 8; ++k) {
            int p = pX(base + (k << 3));
            X0r[p] = y0[k].r; X0i[p] = y0[k].i;
            X1r[p] = y1[k].r; X1i[p] = y1[k].i;
        }
    }
    __syncthreads();
    // DIT C (7,8,9)
    {
        int base = ((tid >> 6) << 9) + (tid & 63);
#pragma unroll
        for (int k = 0; k < 8; ++k) {
            int p = pX(base + (k << 6));
            y0[k] = mkc(X0r[p], X0i[p]);
            y1[k] = mkc(X1r[p], X1i[p]);
        }
        c32 w3 = wexp((tid & 63) << 2);
        dit8_tw(y0, w3);
        dit8_tw(y1, w3);
#pragma unroll
        for (int k = 0; k < 8; ++k) {
            int p = pX(base + (k << 6));
            X0r[p] = y0[k].r; X0i[p] = y0[k].i;
            X1r[p] = y1[k].r; X1i[p] = y1[k].i;
        }
    }
    __syncthreads();
    // DIT D (10,11) radix-4 + masked |.|^2, both rows; per-wave atomicAdd
    float local = 0.f;
#pragma unroll
    for (int h = 0; h < 2; ++h) {
        int pos = tid + (h << 8);
        c32 w = wexp(pos);
        c32 z0[4], z1[4];
#pragma unroll
        for (int k = 0; k < 4; ++k) {
            int p = pX(pos + (k << 9));
            z0[k] = mkc(X0r[p], X0i[p]);
            z1[k] = mkc(X1r[p], X1i[p]);
        }
        dit4(z0, w);
        dit4(z1, w);
        local += z0[0].r * z0[0].r + z0[0].i * z0[0].i
               + z1[0].r * z1[0].r + z1[0].i * z1[0].i;                 // s = pos < 514 always
        if (pos < 2)  local += z0[1].r * z0[1].r + z0[1].i * z0[1].i
                             + z1[1].r * z1[1].r + z1[1].i * z1[1].i;   // s in {512,513}
        if (pos >= 1) local += z0[3].r * z0[3].r + z0[3].i * z0[3].i
                             + z1[3].r * z1[3].r + z1[3].i * z1[3].i;   // s >= 1537
    }
    local *= (n == 0 || n == 256) ? 1.0f : 2.0f;       // mirror-row weight
#pragma unroll
    for (int off = 32; off >= 1; off >>= 1) local += __shfl_down(local, off);
    if ((tid & 63) == 0) {
        const float SCALE =
            (float)(1.0 / ((double)MFFT * (double)MFFT * (double)BATCH * (double)T_FRAMES));
        atomicAdd(out, local * SCALE);
    }
}

extern "C" void kernel_launch(void* const* d_in, const int* in_sizes, int n_in,
                              void* d_out, int out_size, void* d_ws, size_t ws_size,
                              hipStream_t stream) {
    (void)in_sizes; (void)n_in; (void)out_size; (void)ws_size;
    const float* wave   = (const float*)d_in[0];
    const float* window = (const float*)d_in[1];
    const float* ar     = (const float*)d_in[2];
    const float* ai     = (const float*)d_in[3];
    float* out = (float*)d_out;

    char* ws = (char*)d_ws;
    float2* Ht   = (float2*)ws;                          // 4*512*1032*8 = 16,908,288 B
    float2* Afbr = (float2*)(ws + 16908288);             // 7*2048*8    =    114,688 B

    stage1_kernel<<<524, 256, 0, stream>>>(wave, window, ar, ai, Ht, Afbr, out);
    conv_kernel<<<2 * 257, 256, 0, stream>>>(Ht, Afbr, out);
}

// Round 16
// 85.975 us; speedup vs baseline: 1.5472x; 1.2313x over previous
//
#include <hip/hip_runtime.h>
#include <math.h>

#define T_FRAMES 1025
#define TSTRIDE  1032          // row stride for Ht; 1032*8 = 129*64 -> rows 64B-aligned
#define BATCH    4
#define LWAV     131072
#define KWC      1023
#define MFFT     2048
#define PI_F     3.14159265358979323846f

struct c32 { float r, i; };
__device__ __forceinline__ c32 mkc(float r, float i){ c32 z; z.r=r; z.i=i; return z; }
__device__ __forceinline__ c32 cadd(c32 a, c32 b){ return mkc(a.r+b.r, a.i+b.i); }
__device__ __forceinline__ c32 csub(c32 a, c32 b){ return mkc(a.r-b.r, a.i-b.i); }
__device__ __forceinline__ c32 cmul(c32 a, c32 b){ return mkc(a.r*b.r - a.i*b.i, a.r*b.i + a.i*b.r); }
__device__ __forceinline__ c32 cni(c32 a){ return mkc(a.i, -a.r); }           // a * (-i)
#define C8F 0.70710678118654752440f
__device__ __forceinline__ c32 c8p(c32 a){ return mkc(C8F*(a.r+a.i), C8F*(a.i-a.r)); }   // * e^{-i pi/4}
__device__ __forceinline__ c32 c8m(c32 a){ return mkc(C8F*(a.i-a.r), -C8F*(a.r+a.i)); }  // * e^{-i 3pi/4}

__device__ __forceinline__ int pX(int j){ return j + (j >> 5); }
__device__ __forceinline__ int pS(int j){ return j + (j >> 3); }
__device__ __forceinline__ int rev9(int j){ return (int)(__brev((unsigned)j) >> 23); }

// e^{-2*pi*i*r/2048} via fast HW sincos
__device__ __forceinline__ c32 wexp(int r) {
    float s, c;
    __sincosf((float)r * (-PI_F / 1024.0f), &s, &c);
    return mkc(c, s);
}

// ---- radix-8 DIF step; w3 = W^{pos} of current level
__device__ __forceinline__ void dif8_tw(c32 y[8], c32 w3) {
    c32 w2 = cmul(w3, w3), w1 = cmul(w2, w2);
    c32 u[8], v[8], d;
    d = csub(y[0], y[4]); u[0] = cadd(y[0], y[4]); u[4] = cmul(d, w3);
    d = csub(y[1], y[5]); u[1] = cadd(y[1], y[5]); u[5] = c8p(cmul(d, w3));
    d = csub(y[2], y[6]); u[2] = cadd(y[2], y[6]); u[6] = cni(cmul(d, w3));
    d = csub(y[3], y[7]); u[3] = cadd(y[3], y[7]); u[7] = c8m(cmul(d, w3));
    d = csub(u[0], u[2]); v[0] = cadd(u[0], u[2]); v[2] = cmul(d, w2);
    d = csub(u[1], u[3]); v[1] = cadd(u[1], u[3]); v[3] = cni(cmul(d, w2));
    d = csub(u[4], u[6]); v[4] = cadd(u[4], u[6]); v[6] = cmul(d, w2);
    d = csub(u[5], u[7]); v[5] = cadd(u[5], u[7]); v[7] = cni(cmul(d, w2));
    d = csub(v[0], v[1]); y[0] = cadd(v[0], v[1]); y[1] = cmul(d, w1);
    d = csub(v[2], v[3]); y[2] = cadd(v[2], v[3]); y[3] = cmul(d, w1);
    d = csub(v[4], v[5]); y[4] = cadd(v[4], v[5]); y[5] = cmul(d, w1);
    d = csub(v[6], v[7]); y[6] = cadd(v[6], v[7]); y[7] = cmul(d, w1);
}
__device__ __forceinline__ void dif8_nt(c32 y[8]) {
    c32 u[8], v[8], d;
    d = csub(y[0], y[4]); u[0] = cadd(y[0], y[4]); u[4] = d;
    d = csub(y[1], y[5]); u[1] = cadd(y[1], y[5]); u[5] = c8p(d);
    d = csub(y[2], y[6]); u[2] = cadd(y[2], y[6]); u[6] = cni(d);
    d = csub(y[3], y[7]); u[3] = cadd(y[3], y[7]); u[7] = c8m(d);
    d = csub(u[0], u[2]); v[0] = cadd(u[0], u[2]); v[2] = d;
    d = csub(u[1], u[3]); v[1] = cadd(u[1], u[3]); v[3] = cni(d);
    d = csub(u[4], u[6]); v[4] = cadd(u[4], u[6]); v[6] = d;
    d = csub(u[5], u[7]); v[5] = cadd(u[5], u[7]); v[7] = cni(d);
    d = csub(v[0], v[1]); y[0] = cadd(v[0], v[1]); y[1] = d;
    d = csub(v[2], v[3]); y[2] = cadd(v[2], v[3]); y[3] = d;
    d = csub(v[4], v[5]); y[4] = cadd(v[4], v[5]); y[5] = d;
    d = csub(v[6], v[7]); y[6] = cadd(v[6], v[7]); y[7] = d;
}
__device__ __forceinline__ void dit8_tw(c32 y[8], c32 w3) {
    c32 w2 = cmul(w3, w3), w1 = cmul(w2, w2);
    c32 u[8], v[8], t;
    t = cmul(y[1], w1); u[0] = cadd(y[0], t); u[1] = csub(y[0], t);
    t = cmul(y[3], w1); u[2] = cadd(y[2], t); u[3] = csub(y[2], t);
    t = cmul(y[5], w1); u[4] = cadd(y[4], t); u[5] = csub(y[4], t);
    t = cmul(y[7], w1); u[6] = cadd(y[6], t); u[7] = csub(y[6], t);
    t = cmul(u[2], w2);      v[0] = cadd(u[0], t); v[2] = csub(u[0], t);
    t = cni(cmul(u[3], w2)); v[1] = cadd(u[1], t); v[3] = csub(u[1], t);
    t = cmul(u[6], w2);      v[4] = cadd(u[4], t); v[6] = csub(u[4], t);
    t = cni(cmul(u[7], w2)); v[5] = cadd(u[5], t); v[7] = csub(u[5], t);
    t = cmul(v[4], w3);      y[0] = cadd(v[0], t); y[4] = csub(v[0], t);
    t = c8p(cmul(v[5], w3)); y[1] = cadd(v[1], t); y[5] = csub(v[1], t);
    t = cni(cmul(v[6], w3)); y[2] = cadd(v[2], t); y[6] = csub(v[2], t);
    t = c8m(cmul(v[7], w3)); y[3] = cadd(v[3], t); y[7] = csub(v[3], t);
}
__device__ __forceinline__ void dit8_nt(c32 y[8]) {
    c32 u[8], v[8], t;
    u[0] = cadd(y[0], y[1]); u[1] = csub(y[0], y[1]);
    u[2] = cadd(y[2], y[3]); u[3] = csub(y[2], y[3]);
    u[4] = cadd(y[4], y[5]); u[5] = csub(y[4], y[5]);
    u[6] = cadd(y[6], y[7]); u[7] = csub(y[6], y[7]);
    t = u[2];      v[0] = cadd(u[0], t); v[2] = csub(u[0], t);
    t = cni(u[3]); v[1] = cadd(u[1], t); v[3] = csub(u[1], t);
    t = u[6];      v[4] = cadd(u[4], t); v[6] = csub(u[4], t);
    t = cni(u[7]); v[5] = cadd(u[5], t); v[7] = csub(u[5], t);
    t = v[4];      y[0] = cadd(v[0], t); y[4] = csub(v[0], t);
    t = c8p(v[5]); y[1] = cadd(v[1], t); y[5] = csub(v[1], t);
    t = cni(v[6]); y[2] = cadd(v[2], t); y[6] = csub(v[2], t);
    t = c8m(v[7]); y[3] = cadd(v[3], t); y[7] = csub(v[3], t);
}
__device__ __forceinline__ void dif4(c32 y[4]) {
    c32 u0 = cadd(y[0], y[2]), d0 = csub(y[0], y[2]);
    c32 u1 = cadd(y[1], y[3]), d1 = cni(csub(y[1], y[3]));
    y[0] = cadd(u0, u1); y[1] = csub(u0, u1);
    y[2] = cadd(d0, d1); y[3] = csub(d0, d1);
}
__device__ __forceinline__ void dit4(c32 y[4], c32 w) {
    c32 w2 = cmul(w, w);
    c32 t1 = cmul(y[1], w2); c32 u0 = cadd(y[0], t1), u1 = csub(y[0], t1);
    c32 t3 = cmul(y[3], w2); c32 u2 = cadd(y[2], t3), u3 = csub(y[2], t3);
    c32 s2 = cmul(u2, w);      y[0] = cadd(u0, s2); y[2] = csub(u0, s2);
    c32 s3 = cni(cmul(u3, w)); y[1] = cadd(u1, s3); y[3] = csub(u1, s3);
}

// ---------------- stage1: blocks 0..515 = STFT; 516..522 = alpha-FFT; 523 zeroes out.
__global__ __launch_bounds__(256) void stage1_kernel(const float* __restrict__ wave,
                                                     const float* __restrict__ win,
                                                     const float* __restrict__ ar,
                                                     const float* __restrict__ ai,
                                                     float2* __restrict__ Ht,
                                                     float2* __restrict__ Afbr,
                                                     float* __restrict__ out) {
    __shared__ float lds[9216];      // stft: Fr[8][576] | Fi[8][576]; afft: Xr[2112] | Xi[2112]
    const int tid = threadIdx.x;

    if (blockIdx.x < 516) {
        float* Fr = lds;             // [8][576] flattened
        float* Fi = lds + 4608;
        const int w = tid >> 6, l = tid & 63;
        const int b = blockIdx.x / 129;
        const int t0 = (blockIdx.x - b * 129) << 3;
        const float* wb = wave + (size_t)b * LWAV;

        for (int pass = 0; pass < 2; ++pass) {
            const int j = w + (pass << 2);
            const int t = t0 + j;
            if (t < T_FRAMES) {
                c32 y[8];
#pragma unroll
                for (int k = 0; k < 8; ++k) {
                    int s = l + (k << 6);
                    int posn = t * 128 + s - 256;
                    int ix = posn < 0 ? -posn : (posn >= LWAV ? 2 * LWAV - 2 - posn : posn);
                    y[k] = mkc(wb[ix] * win[s], 0.f);
                }
                dif8_tw(y, wexp(l << 2));
#pragma unroll
                for (int k = 0; k < 8; ++k) { int p = pS(l + (k << 6)); Fr[j*576+p] = y[k].r; Fi[j*576+p] = y[k].i; }
                __builtin_amdgcn_wave_barrier();
                {
                    int base = ((l >> 3) << 6) + (l & 7);
#pragma unroll
                    for (int k = 0; k < 8; ++k) { int p = pS(base + (k << 3)); y[k] = mkc(Fr[j*576+p], Fi[j*576+p]); }
                    dif8_tw(y, wexp((l & 7) << 5));
#pragma unroll
                    for (int k = 0; k < 8; ++k) { int p = pS(base + (k << 3)); Fr[j*576+p] = y[k].r; Fi[j*576+p] = y[k].i; }
                }
                __builtin_amdgcn_wave_barrier();
                {
#pragma unroll
                    for (int k = 0; k < 8; ++k) { int p = pS((l << 3) + k); y[k] = mkc(Fr[j*576+p], Fi[j*576+p]); }
                    dif8_nt(y);
#pragma unroll
                    for (int k = 0; k < 8; ++k) { int p = pS((l << 3) + k); Fr[j*576+p] = y[k].r; Fi[j*576+p] = y[k].i; }
                }
            }
        }
        __syncthreads();
        // transposed writeout: rows p = tid, tid+256; skip rows whose bin > 256
        const bool full = (t0 + 7 < T_FRAMES);
#pragma unroll
        for (int h = 0; h < 2; ++h) {
            int p = tid + (h << 8);
            int bin = rev9(p);
            if (bin > 256) continue;
            int ps = pS(p);
            size_t rowbase = (size_t)(b * 512 + p) * TSTRIDE + t0;
            if (full) {
                float4* dst = (float4*)(Ht + rowbase);
#pragma unroll
                for (int jj = 0; jj < 4; ++jj)
                    dst[jj] = make_float4(Fr[2*jj*576+ps], Fi[2*jj*576+ps], Fr[(2*jj+1)*576+ps], Fi[(2*jj+1)*576+ps]);
            } else {
                for (int jj = 0; jj < 8; ++jj)
                    if (t0 + jj < T_FRAMES) Ht[rowbase + jj] = make_float2(Fr[jj*576+ps], Fi[jj*576+ps]);
            }
        }
    } else if (blockIdx.x < 523) {
        // ---- alpha FFT: Af_br[q][p] = conj(DIF2048(conj(alpha_q) zero-pad))[p]
        float* Xr = lds;
        float* Xi = lds + 2112;
        const int q = blockIdx.x - 516;
        c32 y[8];
#pragma unroll
        for (int k = 0; k < 8; ++k) {
            int j = tid + (k << 8);
            y[k] = (j < KWC) ? mkc(ar[q * KWC + j], -ai[q * KWC + j]) : mkc(0.f, 0.f);
        }
        dif8_tw(y, wexp(tid));
#pragma unroll
        for (int k = 0; k < 8; ++k) { int p = pX(tid + (k << 8)); Xr[p] = y[k].r; Xi[p] = y[k].i; }
        __syncthreads();
        {
            int base = ((tid >> 5) << 8) + (tid & 31);
#pragma unroll
            for (int k = 0; k < 8; ++k) { int p = pX(base + (k << 5)); y[k] = mkc(Xr[p], Xi[p]); }
            dif8_tw(y, wexp((tid & 31) << 3));
#pragma unroll
            for (int k = 0; k < 8; ++k) { int p = pX(base + (k << 5)); Xr[p] = y[k].r; Xi[p] = y[k].i; }
        }
        __syncthreads();
        {
            int base = ((tid & 63) << 5) + (tid >> 6);
#pragma unroll
            for (int k = 0; k < 8; ++k) { int p = pX(base + (k << 2)); y[k] = mkc(Xr[p], Xi[p]); }
            dif8_tw(y, wexp((tid >> 6) << 6));
#pragma unroll
            for (int k = 0; k < 8; ++k) { int p = pX(base + (k << 2)); Xr[p] = y[k].r; Xi[p] = y[k].i; }
        }
        __syncthreads();
#pragma unroll
        for (int h = 0; h < 2; ++h) {
            int g = tid + (h << 8);
            c32 z4[4];
#pragma unroll
            for (int k = 0; k < 4; ++k) { int p = pX((g << 2) + k); z4[k] = mkc(Xr[p], Xi[p]); }
            dif4(z4);
#pragma unroll
            for (int k = 0; k < 4; ++k) Afbr[(q << 11) + (g << 2) + k] = make_float2(z4[k].r, -z4[k].i);
        }
    } else {
        if (tid == 0) *out = 0.f;
    }
}

// ---------------- conv: TWO rows (b0,n),(b0+1,n) per 256-thread block.
// Rows share all twiddles, phase factors, and the per-element Kk construction;
// two independent dep-chains per phase double ILP for LDS-latency hiding.
__global__ __launch_bounds__(256) void conv_kernel(const float2* __restrict__ Ht,
                                                   const float2* __restrict__ Afbr,
                                                   float* __restrict__ out) {
    __shared__ float lds[8452];   // X0r|X0i|X1r|X1i (4*2112) + red[4]
    float* X0r = lds;
    float* X0i = lds + 2112;
    float* X1r = lds + 4224;
    float* X1i = lds + 6336;
    float* red = lds + 8448;
    const int tid = threadIdx.x;
    const int g = blockIdx.x;                    // 0..513
    const int half = g / 257;
    const int n = g - half * 257;                // bin 0..256
    const int b0 = half << 1;
    const int pr = rev9(n);                      // Ht row holding bin n

    const float2* row0 = Ht + (size_t)(b0 * 512 + pr) * TSTRIDE;
    const float2* row1 = Ht + (size_t)((b0 + 1) * 512 + pr) * TSTRIDE;

    c32 y0[8], y1[8];
    // DIF A (11,10,9): elements tid + 256k
#pragma unroll
    for (int k = 0; k < 8; ++k) {
        int j = tid + (k << 8);
        c32 v0 = mkc(0.f, 0.f), v1 = mkc(0.f, 0.f);
        if (j < T_FRAMES) {
            float2 h0 = row0[j]; v0 = mkc(h0.x, h0.y);
            float2 h1 = row1[j]; v1 = mkc(h1.x, h1.y);
        }
        y0[k] = v0; y1[k] = v1;
    }
    {
        c32 w3 = wexp(tid);
        dif8_tw(y0, w3);
        dif8_tw(y1, w3);
#pragma unroll
        for (int k = 0; k < 8; ++k) {
            int p = pX(tid + (k << 8));
            X0r[p] = y0[k].r; X0i[p] = y0[k].i;
            X1r[p] = y1[k].r; X1i[p] = y1[k].i;
        }
    }
    __syncthreads();
    // DIF B (8,7,6)
    {
        int base = ((tid >> 5) << 8) + (tid & 31);
#pragma unroll
        for (int k = 0; k < 8; ++k) {
            int p = pX(base + (k << 5));
            y0[k] = mkc(X0r[p], X0i[p]);
            y1[k] = mkc(X1r[p], X1i[p]);
        }
        c32 w3 = wexp((tid & 31) << 3);
        dif8_tw(y0, w3);
        dif8_tw(y1, w3);
#pragma unroll
        for (int k = 0; k < 8; ++k) {
            int p = pX(base + (k << 5));
            X0r[p] = y0[k].r; X0i[p] = y0[k].i;
            X1r[p] = y1[k].r; X1i[p] = y1[k].i;
        }
    }
    __syncthreads();
    // DIF C (5,4,3)
    {
        int base = ((tid & 63) << 5) + (tid >> 6);
#pragma unroll
        for (int k = 0; k < 8; ++k) {
            int p = pX(base + (k << 2));
            y0[k] = mkc(X0r[p], X0i[p]);
            y1[k] = mkc(X1r[p], X1i[p]);
        }
        c32 w3 = wexp((tid >> 6) << 6);
        dif8_tw(y0, w3);
        dif8_tw(y1, w3);
#pragma unroll
        for (int k = 0; k < 8; ++k) {
            int p = pX(base + (k << 2));
            X0r[p] = y0[k].r; X0i[p] = y0[k].i;
            X1r[p] = y1[k].r; X1i[p] = y1[k].i;
        }
    }
    __syncthreads();
    // FUSED: DIF D (radix-4 x2) + pointwise (Kk computed ONCE for both rows) + DIT A
    {
        c32 p1 = wexp(-(n << 2));                      // e^{+2pi i n/512}
        c32 p2 = cmul(p1, p1);
        c32 p3 = cmul(p2, p1);
        const int a0 = tid << 3;
        const int p0 = pX(a0);
#pragma unroll
        for (int k = 0; k < 8; ++k) {
            y0[k] = mkc(X0r[p0 + k], X0i[p0 + k]);
            y1[k] = mkc(X1r[p0 + k], X1i[p0 + k]);
        }
        dif4(&y0[0]); dif4(&y0[4]);
        dif4(&y1[0]); dif4(&y1[4]);
        const float4* af4 = (const float4*)(Afbr + a0);
#pragma unroll
        for (int k = 0; k < 8; ++k) {
            float4 a;
            c32 Kk;
            a = af4[(3 << 10) + (k >> 1)];     // q'=0
            float ax = (k & 1) ? a.z : a.x, ay = (k & 1) ? a.w : a.y;
            Kk = mkc(ax, ay);
            a = af4[(4 << 10) + (k >> 1)]; ax = (k & 1) ? a.z : a.x; ay = (k & 1) ? a.w : a.y;
            Kk.r += p1.r * ax - p1.i * ay;  Kk.i += p1.r * ay + p1.i * ax;
            a = af4[(2 << 10) + (k >> 1)]; ax = (k & 1) ? a.z : a.x; ay = (k & 1) ? a.w : a.y;
            Kk.r += p1.r * ax + p1.i * ay;  Kk.i += p1.r * ay - p1.i * ax;
            a = af4[(5 << 10) + (k >> 1)]; ax = (k & 1) ? a.z : a.x; ay = (k & 1) ? a.w : a.y;
            Kk.r += p2.r * ax - p2.i * ay;  Kk.i += p2.r * ay + p2.i * ax;
            a = af4[(1 << 10) + (k >> 1)]; ax = (k & 1) ? a.z : a.x; ay = (k & 1) ? a.w : a.y;
            Kk.r += p2.r * ax + p2.i * ay;  Kk.i += p2.r * ay - p2.i * ax;
            a = af4[(6 << 10) + (k >> 1)]; ax = (k & 1) ? a.z : a.x; ay = (k & 1) ? a.w : a.y;
            Kk.r += p3.r * ax - p3.i * ay;  Kk.i += p3.r * ay + p3.i * ax;
            a = af4[(0 << 10) + (k >> 1)]; ax = (k & 1) ? a.z : a.x; ay = (k & 1) ? a.w : a.y;
            Kk.r += p3.r * ax + p3.i * ay;  Kk.i += p3.r * ay - p3.i * ax;
            c32 P0 = cmul(y0[k], Kk);
            c32 P1 = cmul(y1[k], Kk);
            y0[k] = mkc(P0.r, -P0.i);          // conj for inverse-via-forward
            y1[k] = mkc(P1.r, -P1.i);
        }
        dit8_nt(y0);
        dit8_nt(y1);
#pragma unroll
        for (int k = 0; k < 8; ++k) {
            X0r[p0 + k] = y0[k].r; X0i[p0 + k] = y0[k].i;
            X1r[p0 + k] = y1[k].r; X1i[p0 + k] = y1[k].i;
        }
    }
    __syncthreads();
    // DIT B (4,5,6)
    {
        int G = (((tid & 63) >> 3) << 2) + (tid >> 6);
        int pos = tid & 7;
        int base = (G << 6) + pos;
#pragma unroll
        for (int k = 0; k < 8; ++k) {
            int p = pX(base + (k << 3));
            y0[k] = mkc(X0r[p], X0i[p]);
            y1[k] = mkc(X1r[p], X1i[p]);
        }
        c32 w3 = wexp(pos << 5);
        dit8_tw(y0, w3);
        dit8_tw(y1, w3);
#pragma unroll
        for (int k = 0; k < 8; ++k) {
            int p = pX(base + (k << 3));
            X0r[p] = y0[k].r; X0i[p] = y0[k].i;
            X1r[p] = y1[k].r; X1i[p] = y1[k].i;
        }
    }
    __syncthreads();
    // DIT C (7,8,9)
    {
        int base = ((tid >> 6) << 9) + (tid & 63);
#pragma unroll
        for (int k = 0; k < 8; ++k) {
            int p = pX(base + (k << 6));
            y0[k] = mkc(X0r[p], X0i[p]);
            y1[k] = mkc(X1r[p], X1i[p]);
        }
        c32 w3 = wexp((tid & 63) << 2);
        dit8_tw(y0, w3);
        dit8_tw(y1, w3);
#pragma unroll
        for (int k = 0; k < 8; ++k) {
            int p = pX(base + (k << 6));
            X0r[p] = y0[k].r; X0i[p] = y0[k].i;
            X1r[p] = y1[k].r; X1i[p] = y1[k].i;
        }
    }
    __syncthreads();
    // DIT D (10,11) radix-4 + masked |.|^2, both rows
    float local = 0.f;
#pragma unroll
    for (int h = 0; h < 2; ++h) {
        int pos = tid + (h << 8);
        c32 w = wexp(pos);
        c32 z0[4], z1[4];
#pragma unroll
        for (int k = 0; k < 4; ++k) {
            int p = pX(pos + (k << 9));
            z0[k] = mkc(X0r[p], X0i[p]);
            z1[k] = mkc(X1r[p], X1i[p]);
        }
        dit4(z0, w);
        dit4(z1, w);
        local += z0[0].r * z0[0].r + z0[0].i * z0[0].i
               + z1[0].r * z1[0].r + z1[0].i * z1[0].i;                 // s = pos < 514 always
        if (pos < 2)  local += z0[1].r * z0[1].r + z0[1].i * z0[1].i
                             + z1[1].r * z1[1].r + z1[1].i * z1[1].i;   // s in {512,513}
        if (pos >= 1) local += z0[3].r * z0[3].r + z0[3].i * z0[3].i
                             + z1[3].r * z1[3].r + z1[3].i * z1[3].i;   // s >= 1537
    }
    local *= (n == 0 || n == 256) ? 1.0f : 2.0f;       // mirror-row weight
#pragma unroll
    for (int off = 32; off >= 1; off >>= 1) local += __shfl_down(local, off);
    if ((tid & 63) == 0) red[tid >> 6] = local;
    __syncthreads();
    if (tid == 0) {
        const float SCALE =
            (float)(1.0 / ((double)MFFT * (double)MFFT * (double)BATCH * (double)T_FRAMES));
        atomicAdd(out, (red[0] + red[1] + red[2] + red[3]) * SCALE);
    }
}

extern "C" void kernel_launch(void* const* d_in, const int* in_sizes, int n_in,
                              void* d_out, int out_size, void* d_ws, size_t ws_size,
                              hipStream_t stream) {
    (void)in_sizes; (void)n_in; (void)out_size; (void)ws_size;
    const float* wave   = (const float*)d_in[0];
    const float* window = (const float*)d_in[1];
    const float* ar     = (const float*)d_in[2];
    const float* ai     = (const float*)d_in[3];
    float* out = (float*)d_out;

    char* ws = (char*)d_ws;
    float2* Ht   = (float2*)ws;                          // 4*512*1032*8 = 16,908,288 B
    float2* Afbr = (float2*)(ws + 16908288);             // 7*2048*8    =    114,688 B

    stage1_kernel<<<524, 256, 0, stream>>>(wave, window, ar, ai, Ht, Afbr, out);
    conv_kernel<<<2 * 257, 256, 0, stream>>>(Ht, Afbr, out);
}